// Round 1
// 450.717 us; speedup vs baseline: 1.1638x; 1.1638x over previous
//
#include <hip/hip_runtime.h>

// Elman RNN (relu), B=4096 T=4096 H=32, fp32 in/out.
// h_new[j] = relu( sum_k W_hh[j,k] h[k] + x*W_ih[j] + b_ih[j]+b_hh[j] )
//
// R10: the wave is ISSUE-bound (VALUBusy 15.9% CU-avg = ~64% on the active
// SIMD; MfmaUtil ~12% on-SIMD; only ~24% stall). Per-step issue budget was
// 20 wave64 VALU (8 fma C-build + 8 max + 4 cvt_pkrtz) = ~40 cyc + 2 MFMA.
// This round cuts VALU/step ~20 -> ~14 with VOP3P packed math:
//   - C-build: 4x v_pk_fma_f32 (float2 elementwise_fma) + (x,x) pair build
//   - relu moved AFTER the f16 pack: 4x cvt_pkrtz + 4x v_pk_max_f16
//     (bit-identical: max(rtz(d),0) == rtz(max(d,0)) elementwise)
// Final-step f32 d values stay live (d1g/d2g) so the output epilogue is
// bit-identical to R9 (no extra f16 rounding in the checked output).
//
// MFMA mapping (unchanged from R8/R9):
//   A1 row m computes unit u1(m)=8*(m>>2)+(m&3); A2 row m -> u1(m)+4.
//   Lane (batch n=lane&15, quad q) exits with units 8q..8q+7 = B fragment,
//   so D-layout == next B-layout with zero cross-lane transform.
// 256 blocks x 64 thr = 1 wave/CU, 16 batches per wave.

#define HSZ 32

typedef _Float16 half8 __attribute__((ext_vector_type(8)));
typedef _Float16 h2n __attribute__((ext_vector_type(2)));
typedef __fp16 fp16x2 __attribute__((ext_vector_type(2)));
typedef float f32x4 __attribute__((ext_vector_type(4)));
typedef float f32x2 __attribute__((ext_vector_type(2)));

// relu on a packed f16 pair: v_pk_max_f16 with inline 0.
static __device__ __forceinline__ fp16x2 relu_pk(fp16x2 a) {
  union {
    fp16x2 r;
    h2n n;
  } u;
  u.r = a;
  h2n z = {(_Float16)0.f, (_Float16)0.f};
  u.n = __builtin_elementwise_max(u.n, z);
  return u.r;
}

__global__ __attribute__((amdgpu_flat_work_group_size(64, 64),
                          amdgpu_waves_per_eu(1, 1)))
void rnn_reg_kernel(
    const float* __restrict__ x, const float* __restrict__ h_init,
    const float* __restrict__ W_ih, const float* __restrict__ W_hh,
    const float* __restrict__ b_ih, const float* __restrict__ b_hh,
    const float* __restrict__ W_reg, const float* __restrict__ b_reg,
    float* __restrict__ out, int T) {
  const int lane = threadIdx.x;             // 0..63
  const int lo4  = lane & 15;               // batch column n / A row m
  const int q    = lane >> 4;               // quad 0..3
  const int bg   = blockIdx.x * 16 + lo4;   // this lane's batch

  // Permuted A rows: row m of A1 is W_hh[u1(m)], row m of A2 is W_hh[u1(m)+4]
  const int u1m = 8 * (lo4 >> 2) + (lo4 & 3);
  half8 A1, A2;
#pragma unroll
  for (int j = 0; j < 8; ++j) {
    A1[j] = (_Float16)W_hh[u1m * HSZ + 8 * q + j];          // v_cvt_f16_f32 RNE
    A2[j] = (_Float16)W_hh[(u1m + 4) * HSZ + 8 * q + j];
  }

  // C-build constants as f32 pairs for v_pk_fma_f32.
  // D1 reg r is unit 8q+r, D2 reg r is unit 8q+4+r.
  const int m0 = 8 * q;
  f32x2 wih1a = {W_ih[m0 + 0], W_ih[m0 + 1]};
  f32x2 wih1b = {W_ih[m0 + 2], W_ih[m0 + 3]};
  f32x2 wih2a = {W_ih[m0 + 4], W_ih[m0 + 5]};
  f32x2 wih2b = {W_ih[m0 + 6], W_ih[m0 + 7]};
  f32x2 bia1a = {b_ih[m0 + 0] + b_hh[m0 + 0], b_ih[m0 + 1] + b_hh[m0 + 1]};
  f32x2 bia1b = {b_ih[m0 + 2] + b_hh[m0 + 2], b_ih[m0 + 3] + b_hh[m0 + 3]};
  f32x2 bia2a = {b_ih[m0 + 4] + b_hh[m0 + 4], b_ih[m0 + 5] + b_hh[m0 + 5]};
  f32x2 bia2b = {b_ih[m0 + 6] + b_hh[m0 + 6], b_ih[m0 + 7] + b_hh[m0 + 7]};

  // Initial B fragment from h_init: B[k=8q+i][n=lo4]
  half8 bfrag;
#pragma unroll
  for (int i = 0; i < 8; ++i)
    bfrag[i] = (_Float16)h_init[(size_t)bg * HSZ + 8 * q + i];

  // Final-step f32 MFMA outputs, live across the loop for the epilogue
  // (bit-identical output vs computing from the f16 state).
  f32x4 d1g = {0.f, 0.f, 0.f, 0.f};
  f32x4 d2g = {0.f, 0.f, 0.f, 0.f};

#define STEP(xv)                                                              \
  do {                                                                        \
    f32x2 xx = {(xv), (xv)};                                                  \
    f32x2 p0 = __builtin_elementwise_fma(wih1a, xx, bia1a);                   \
    f32x2 p1 = __builtin_elementwise_fma(wih1b, xx, bia1b);                   \
    f32x2 p2 = __builtin_elementwise_fma(wih2a, xx, bia2a);                   \
    f32x2 p3 = __builtin_elementwise_fma(wih2b, xx, bia2b);                   \
    f32x4 c1 = __builtin_shufflevector(p0, p1, 0, 1, 2, 3);                   \
    f32x4 c2 = __builtin_shufflevector(p2, p3, 0, 1, 2, 3);                   \
    f32x4 d1 = __builtin_amdgcn_mfma_f32_16x16x32_f16(A1, bfrag, c1, 0, 0, 0);\
    f32x4 d2 = __builtin_amdgcn_mfma_f32_16x16x32_f16(A2, bfrag, c2, 0, 0, 0);\
    d1g = d1;                                                                 \
    d2g = d2;                                                                 \
    union { fp16x2 h2[4]; half8 h8; } cv;                                     \
    cv.h2[0] = relu_pk(__builtin_amdgcn_cvt_pkrtz(d1[0], d1[1])); /* 8q+0,1 */\
    cv.h2[1] = relu_pk(__builtin_amdgcn_cvt_pkrtz(d1[2], d1[3])); /* 8q+2,3 */\
    cv.h2[2] = relu_pk(__builtin_amdgcn_cvt_pkrtz(d2[0], d2[1])); /* 8q+4,5 */\
    cv.h2[3] = relu_pk(__builtin_amdgcn_cvt_pkrtz(d2[2], d2[3])); /* 8q+6,7 */\
    bfrag = cv.h8;                                                            \
  } while (0)

  // x feed: lane reads its batch's row; quads 4x redundant (L1 absorbs).
  // 2-deep float4 rotation = 8-step prefetch distance.
  const float4* xr = (const float4*)(x + (size_t)bg * (size_t)T);
  const int last = T / 4 - 1;
  float4 xa = xr[0], xb = xr[1];

#pragma unroll 1
  for (int t = 0; t < T; t += 8) {
    int i0 = (t >> 2) + 2; if (i0 > last) i0 = last;
    int i1 = (t >> 2) + 3; if (i1 > last) i1 = last;
    float4 na = xr[i0];
    float4 nb = xr[i1];
    STEP(xa.x); STEP(xa.y); STEP(xa.z); STEP(xa.w);
    STEP(xb.x); STEP(xb.y); STEP(xb.z); STEP(xb.w);
    xa = na; xb = nb;
  }

  // out[bg] = sum_u relu(d[u])*W_reg[u] + b_reg; lane (q,n) holds units
  // 8q+r (d1g) and 8q+4+r (d2g) in f32. Reduce across quads.
  float v = 0.f;
#pragma unroll
  for (int r = 0; r < 4; ++r) {
    v = fmaf(fmaxf(d1g[r], 0.f), W_reg[8 * q + r], v);
    v = fmaf(fmaxf(d2g[r], 0.f), W_reg[8 * q + 4 + r], v);
  }
  v += __shfl_xor(v, 16, 64);
  v += __shfl_xor(v, 32, 64);
  if (q == 0) out[bg] = v + b_reg[0];
}

extern "C" void kernel_launch(void* const* d_in, const int* in_sizes, int n_in,
                              void* d_out, int out_size, void* d_ws, size_t ws_size,
                              hipStream_t stream) {
  const float* x      = (const float*)d_in[0];
  const float* h_init = (const float*)d_in[1];
  const float* W_ih   = (const float*)d_in[2];
  const float* W_hh   = (const float*)d_in[3];
  const float* b_ih   = (const float*)d_in[4];
  const float* b_hh   = (const float*)d_in[5];
  const float* W_reg  = (const float*)d_in[6];
  const float* b_reg  = (const float*)d_in[7];
  float* out = (float*)d_out;

  const int B = in_sizes[1] / HSZ;   // 4096
  const int T = in_sizes[0] / B;     // 4096
  const int grid = B / 16;           // 16 batches per wave/block

  rnn_reg_kernel<<<dim3(grid), dim3(64), 0, stream>>>(
      x, h_init, W_ih, W_hh, b_ih, b_hh, W_reg, b_reg, out, T);
}